// Round 1
// 399.653 us; speedup vs baseline: 1.0363x; 1.0363x over previous
//
#include <hip/hip_runtime.h>

#define SEQ   8192
#define VOCAB 128000
#define L     64
#define NCH   128   // SEQ / L

// ws layout (float offsets)
#define OFF_CMB    0        // CmbT[k][t] : [20][8192] fp32 combined, k-major
#define OFF_CVEC   163840   // cvecT[k][m][i] : [64][128][10]
#define OFF_AMAX   245760   // amax64[t] : 8192 x u64 packed
#define OFF_AMAX1  262144   // amax1[t] : 8192 x u32 sortable approx max
#define OFF_CNORM  270336   // ||c_t||_2 augmented
#define OFF_WPART  278528   // per-block W-norm partials (500)
#define OFF_WMAX   279040   // final wmax (float)
#define OFF_C32    279104   // c32[t][32] bf16 (131072 floats)
#define OFF_W32    410176   // W32[v][32] bf16 (2048000 floats)
// total 2,458,176 floats = 9.83 MB

#define TBLK   16    // t-blocks of 512 t
#define VSLICE 100   // v-slices of 1280 v
#define CHUNKS 5     // 256-row chunks per slice
#define CCAP   2048
#define SEEDSL 4     // v-slices sampled by k_seed (5120 of 128000 v)

typedef __attribute__((ext_vector_type(8))) short bf16x8;
typedef __attribute__((ext_vector_type(4))) float f32x4;

static __device__ inline unsigned short f2bf(float x) {
    unsigned u = __float_as_uint(x);
    u += 0x7FFF + ((u >> 16) & 1);          // RNE
    return (unsigned short)(u >> 16);
}
static __device__ inline unsigned sortable(float x) {
    unsigned u = __float_as_uint(x);
    return (u & 0x80000000u) ? ~u : (u | 0x80000000u);
}
static __device__ inline float unsortable(unsigned k) {
    unsigned u = (k & 0x80000000u) ? (k & 0x7FFFFFFFu) : ~k;
    return __uint_as_float(u);
}

// ---------------------------------------------------------------------------
// K1 (k_prep): blocks 0..31 = embed (+ zero amax/amax1); blocks 32..531 =
// pack [W_v,b_v] -> bf16[v][32] + per-block augmented-norm partial (no
// atomics, no init ordering hazard).
// ---------------------------------------------------------------------------
__global__ void k_prep(const int* __restrict__ ix, const float* __restrict__ emb,
                       const float* __restrict__ Wih, const float* __restrict__ bih,
                       const float* __restrict__ Wio, const float* __restrict__ bio,
                       float* __restrict__ ws) {
    int b = blockIdx.x;
    int tid = threadIdx.x;
    if (b < 32) {
        int t = b * 256 + tid;
        ((unsigned long long*)(ws + OFF_AMAX))[t] = 0ULL;
        ((unsigned*)(ws + OFF_AMAX1))[t] = 0u;

        int id = ix[t];
        float w[10];
        const float2* ep = (const float2*)(emb + (long long)id * 10);
#pragma unroll
        for (int j = 0; j < 5; j++) ((float2*)w)[j] = ep[j];
#pragma unroll
        for (int j = 0; j < 10; j++) ws[OFF_CMB + j * SEQ + t] = w[j];

        int m = t >> 6, k = t & 63;
        float* cv = ws + OFF_CVEC + (k * NCH + m) * 10;
#pragma unroll
        for (int i = 0; i < 10; i++) {
            float s = bih[i];
#pragma unroll
            for (int j = 0; j < 10; j++) s += Wih[i * 20 + j] * w[j];
            cv[i] = s;
        }
    } else {
        __shared__ float red[4];
        int bs = b - 32;
        int v = bs * 256 + tid;
        float w[20];
        const float4* r = (const float4*)(Wio + (long long)v * 20);
#pragma unroll
        for (int q = 0; q < 5; q++) ((float4*)w)[q] = r[q];
        float bv = bio[v];
        float n2 = bv * bv;
#pragma unroll
        for (int k = 0; k < 20; k++) n2 += w[k] * w[k];
        float nrm = sqrtf(n2);
        for (int off = 1; off < 64; off <<= 1)
            nrm = fmaxf(nrm, __shfl_xor(nrm, off));
        if ((tid & 63) == 0) red[tid >> 6] = nrm;
        __syncthreads();
        if (tid == 0)
            ws[OFF_WPART + bs] = fmaxf(fmaxf(red[0], red[1]), fmaxf(red[2], red[3]));

        unsigned short h[32];
#pragma unroll
        for (int k = 0; k < 20; k++) h[k] = f2bf(w[k]);
        h[20] = f2bf(bv);
#pragma unroll
        for (int k = 21; k < 32; k++) h[k] = 0;
        uint4* dst = (uint4*)((unsigned short*)(ws + OFF_W32));
#pragma unroll
        for (int i = 0; i < 4; i++) {
            uint4 u;
            u.x = (unsigned)h[8*i+0] | ((unsigned)h[8*i+1] << 16);
            u.y = (unsigned)h[8*i+2] | ((unsigned)h[8*i+3] << 16);
            u.z = (unsigned)h[8*i+4] | ((unsigned)h[8*i+5] << 16);
            u.w = (unsigned)h[8*i+6] | ((unsigned)h[8*i+7] << 16);
            dst[v * 4 + i] = u;
        }
    }
}

// ---------------------------------------------------------------------------
// K2: blocked scan of h_{t+1} = A h_t + c_t -> CmbT rows 10..19.
// ---------------------------------------------------------------------------
__global__ void k_scan(const float* __restrict__ Wih, float* __restrict__ ws) {
    __shared__ float P[100], Q[100];
    __shared__ float Dl[NCH][10];
    __shared__ float Hst[NCH][10];
    __shared__ float Hl[10];
    int tid = threadIdx.x;

    float Ar[10][10];
#pragma unroll
    for (int i = 0; i < 10; i++)
#pragma unroll
        for (int j = 0; j < 10; j++) Ar[i][j] = Wih[i * 20 + 10 + j];

    {   // phase A
        int m = tid;
        float h[10];
#pragma unroll
        for (int i = 0; i < 10; i++) h[i] = 0.f;
        const float* cvb = ws + OFF_CVEC;
        float2 buf[5];
        {
            const float2* cp = (const float2*)(cvb + m * 10);
#pragma unroll
            for (int j = 0; j < 5; j++) buf[j] = cp[j];
        }
        for (int k = 0; k < L; k++) {
            float cc[10];
#pragma unroll
            for (int j = 0; j < 5; j++) { cc[2*j] = buf[j].x; cc[2*j+1] = buf[j].y; }
            if (k + 1 < L) {
                const float2* cp = (const float2*)(cvb + ((k + 1) * NCH + m) * 10);
#pragma unroll
                for (int j = 0; j < 5; j++) buf[j] = cp[j];
            }
            float nh[10];
#pragma unroll
            for (int i = 0; i < 10; i++) {
                float s = cc[i];
#pragma unroll
                for (int j = 0; j < 10; j++) s += Ar[i][j] * h[j];
                nh[i] = s;
            }
#pragma unroll
            for (int i = 0; i < 10; i++) h[i] = nh[i];
        }
#pragma unroll
        for (int i = 0; i < 10; i++) Dl[m][i] = h[i];
    }

    if (tid < 100) P[tid] = Wih[(tid / 10) * 20 + 10 + (tid % 10)];
    __syncthreads();
    for (int it = 0; it < 6; it++) {
        if (tid < 100) {
            int i = tid / 10, j = tid % 10;
            float s = 0.f;
#pragma unroll
            for (int k = 0; k < 10; k++) s += P[i * 10 + k] * P[k * 10 + j];
            Q[tid] = s;
        }
        __syncthreads();
        if (tid < 100) P[tid] = Q[tid];
        __syncthreads();
    }

    if (tid < 10) Hl[tid] = 0.f;
    __syncthreads();
    if (tid < 10) {
        int i = tid;
        float a64[10];
#pragma unroll
        for (int j = 0; j < 10; j++) a64[j] = P[i * 10 + j];
        float hc = 0.f;
        for (int m = 0; m < NCH; m++) {
            Hst[m][i] = hc;
            float s = Dl[m][i];
#pragma unroll
            for (int j = 0; j < 10; j++) s += a64[j] * Hl[j];
            Hl[i] = s;
            hc = s;
        }
    }
    __syncthreads();

    {   // phase C
        int m = tid;
        float h[10];
#pragma unroll
        for (int i = 0; i < 10; i++) h[i] = Hst[m][i];
        const float* cvb = ws + OFF_CVEC;
        float2 buf[5];
        {
            const float2* cp = (const float2*)(cvb + m * 10);
#pragma unroll
            for (int j = 0; j < 5; j++) buf[j] = cp[j];
        }
        for (int k = 0; k < L; k++) {
            int tg = m * 64 + k;
            float cc[10];
#pragma unroll
            for (int j = 0; j < 5; j++) { cc[2*j] = buf[j].x; cc[2*j+1] = buf[j].y; }
            if (k + 1 < L) {
                const float2* cp = (const float2*)(cvb + ((k + 1) * NCH + m) * 10);
#pragma unroll
                for (int j = 0; j < 5; j++) buf[j] = cp[j];
            }
#pragma unroll
            for (int i = 0; i < 10; i++) ws[OFF_CMB + (10 + i) * SEQ + tg] = h[i];
            float nh[10];
#pragma unroll
            for (int i = 0; i < 10; i++) {
                float s = cc[i];
#pragma unroll
                for (int j = 0; j < 10; j++) s += Ar[i][j] * h[j];
                nh[i] = s;
            }
#pragma unroll
            for (int i = 0; i < 10; i++) h[i] = nh[i];
        }
    }
}

// ---------------------------------------------------------------------------
// K3: blocks 0..31 pack c -> bf16[t][32] (k=20 is 1.0) + augmented norm;
// block 32 reduces the 500 W-norm partials -> wmax (stream-ordered, race-free).
// ---------------------------------------------------------------------------
__global__ void k_pack_c(float* __restrict__ ws) {
    int b = blockIdx.x;
    int tid = threadIdx.x;
    if (b == 32) {
        __shared__ float red[4];
        float m = 0.f;
        for (int i = tid; i < 500; i += 256) m = fmaxf(m, ws[OFF_WPART + i]);
        for (int off = 1; off < 64; off <<= 1)
            m = fmaxf(m, __shfl_xor(m, off));
        if ((tid & 63) == 0) red[tid >> 6] = m;
        __syncthreads();
        if (tid == 0)
            ws[OFF_WMAX] = fmaxf(fmaxf(red[0], red[1]), fmaxf(red[2], red[3]));
        return;
    }
    int t = b * 256 + tid;
    float c[20];
#pragma unroll
    for (int k = 0; k < 20; k++) c[k] = ws[OFF_CMB + k * SEQ + t];
    float n2 = 1.0f;
#pragma unroll
    for (int k = 0; k < 20; k++) n2 += c[k] * c[k];
    ws[OFF_CNORM + t] = sqrtf(n2);

    unsigned short h[32];
#pragma unroll
    for (int k = 0; k < 20; k++) h[k] = f2bf(c[k]);
    h[20] = f2bf(1.0f);
#pragma unroll
    for (int k = 21; k < 32; k++) h[k] = 0;
    uint4* dst = (uint4*)((unsigned short*)(ws + OFF_C32));
#pragma unroll
    for (int i = 0; i < 4; i++) {
        uint4 u;
        u.x = (unsigned)h[8*i+0] | ((unsigned)h[8*i+1] << 16);
        u.y = (unsigned)h[8*i+2] | ((unsigned)h[8*i+3] << 16);
        u.z = (unsigned)h[8*i+4] | ((unsigned)h[8*i+5] << 16);
        u.w = (unsigned)h[8*i+6] | ((unsigned)h[8*i+7] << 16);
        dst[t * 4 + i] = u;
    }
}

// ---------------------------------------------------------------------------
// K4 (k_seed): SAMPLED approx-max via MFMA. Grid 64 = 16 t-blocks x 4
// v-slices (5120 of 128000 v). Scores across v are iid Gaussian per t
// (W is iid normal), so the 5120-sample max sits ~0.7 sigma below the true
// max; thr = sample_max - err is a valid lower-bound threshold (same
// margin argument as before: any attained approx score works as base).
// This replaces the FULL second GEMM pass (~40% of total runtime) with a
// 1/25-sized one. Candidate count in k_cand grows ~4x (to ~70/block),
// still << CCAP, and deterministically so (stream-ordered, no race).
// ---------------------------------------------------------------------------
__global__ __launch_bounds__(256, 2)
void k_seed(const float* __restrict__ ws, unsigned* __restrict__ amax1) {
    __shared__ uint4 Wl4[1024];   // 16 KB, 64 B per v-row

    int tid = threadIdx.x;
    int lane = tid & 63, wid = tid >> 6, quad = lane >> 4, col = lane & 15;
    int tb  = blockIdx.x >> 2;        // 0..15
    int sl  = blockIdx.x & 3;         // 0..3
    int t0w = tb * 512 + wid * 128;
    int v0s = sl * 1280;

    const unsigned short* c32 = (const unsigned short*)(ws + OFF_C32);
    const uint4* W32g = (const uint4*)((const unsigned short*)(ws + OFF_W32));
    const unsigned short* WlS = (const unsigned short*)Wl4;

    bf16x8 a[8];
#pragma unroll
    for (int tt = 0; tt < 8; tt++)
        a[tt] = *(const bf16x8*)(c32 + (t0w + tt * 16 + col) * 32 + quad * 8);

    const f32x4 zero = {0.f, 0.f, 0.f, 0.f};
    float run[8][4];
#pragma unroll
    for (int tt = 0; tt < 8; tt++)
#pragma unroll
        for (int g = 0; g < 4; g++) run[tt][g] = -3.4e38f;

    for (int ch = 0; ch < CHUNKS; ch++) {
        __syncthreads();
        int vb = v0s + ch * 256;
#pragma unroll
        for (int i = 0; i < 4; i++)
            Wl4[tid + 256 * i] = W32g[vb * 4 + tid + 256 * i];
        __syncthreads();

        for (int vt = 0; vt < 16; vt += 2) {
            bf16x8 b0 = *(const bf16x8*)(WlS + (vt * 16 + col) * 32 + quad * 8);
            bf16x8 b1 = *(const bf16x8*)(WlS + ((vt + 1) * 16 + col) * 32 + quad * 8);
#pragma unroll
            for (int tt = 0; tt < 8; tt++) {
                f32x4 d0 = __builtin_amdgcn_mfma_f32_16x16x32_bf16(a[tt], b0, zero, 0, 0, 0);
                f32x4 d1 = __builtin_amdgcn_mfma_f32_16x16x32_bf16(a[tt], b1, zero, 0, 0, 0);
#pragma unroll
                for (int g = 0; g < 4; g++)
                    run[tt][g] = fmaxf(run[tt][g], fmaxf(d0[g], d1[g]));
            }
        }
    }

#pragma unroll
    for (int tt = 0; tt < 8; tt++)
#pragma unroll
        for (int g = 0; g < 4; g++) {
            float r = run[tt][g];
            for (int off = 1; off < 16; off <<= 1)
                r = fmaxf(r, __shfl_xor(r, off));
            if (col == 0)
                atomicMax(&amax1[t0w + tt * 16 + quad * 4 + g], sortable(r));
        }
}

// ---------------------------------------------------------------------------
// K5 (pass 2): candidate pass + inline threshold + LDS candidate list +
// exact fp32 epilogue (packed-u64 atomicMax = exact jnp.argmax semantics).
// Threshold base is now the k_seed sample max (a lower bound of the true
// max); every row's true argmax still satisfies d >= thr, so correctness
// is unchanged — only the candidate count grows (~70/block, CCAP 2048).
// ---------------------------------------------------------------------------
__global__ __launch_bounds__(256, 2)
void k_cand(const float* __restrict__ ws, const float* __restrict__ Wio,
            const float* __restrict__ bio, const unsigned* __restrict__ amax1,
            unsigned long long* __restrict__ amax) {
    __shared__ uint4 Wl4[1024];   // 16 KB
    __shared__ unsigned cand[CCAP];
    __shared__ unsigned cnt;

    int tid = threadIdx.x;
    int lane = tid & 63, wid = tid >> 6, quad = lane >> 4, col = lane & 15;
    int tb  = blockIdx.x / VSLICE;
    int sl  = blockIdx.x % VSLICE;
    int t0w = tb * 512 + wid * 128;
    int v0s = sl * 1280;
    if (tid == 0) cnt = 0;

    const unsigned short* c32 = (const unsigned short*)(ws + OFF_C32);
    const uint4* W32g = (const uint4*)((const unsigned short*)(ws + OFF_W32));
    const unsigned short* WlS = (const unsigned short*)Wl4;
    float wmax = ws[OFF_WMAX];

    bf16x8 a[8];
    float thr[8][4], thrmin[8];
#pragma unroll
    for (int tt = 0; tt < 8; tt++) {
        a[tt] = *(const bf16x8*)(c32 + (t0w + tt * 16 + col) * 32 + quad * 8);
        float mn = 3.4e38f;
#pragma unroll
        for (int g = 0; g < 4; g++) {
            int t = t0w + tt * 16 + quad * 4 + g;
            float maxap = unsortable(amax1[t]);
            thr[tt][g] = maxap - (0.04f * ws[OFF_CNORM + t] * wmax + 1e-5f);
            mn = fminf(mn, thr[tt][g]);
        }
        thrmin[tt] = mn;
    }

    const f32x4 zero = {0.f, 0.f, 0.f, 0.f};

    for (int ch = 0; ch < CHUNKS; ch++) {
        __syncthreads();
        int vb = v0s + ch * 256;
#pragma unroll
        for (int i = 0; i < 4; i++)
            Wl4[tid + 256 * i] = W32g[vb * 4 + tid + 256 * i];
        __syncthreads();

        for (int vt = 0; vt < 16; vt += 2) {
            bf16x8 b0 = *(const bf16x8*)(WlS + (vt * 16 + col) * 32 + quad * 8);
            bf16x8 b1 = *(const bf16x8*)(WlS + ((vt + 1) * 16 + col) * 32 + quad * 8);
            int v0 = vb + vt * 16 + col;
#pragma unroll
            for (int tt = 0; tt < 8; tt++) {
                f32x4 d0 = __builtin_amdgcn_mfma_f32_16x16x32_bf16(a[tt], b0, zero, 0, 0, 0);
                f32x4 d1 = __builtin_amdgcn_mfma_f32_16x16x32_bf16(a[tt], b1, zero, 0, 0, 0);
                // 8-value max as 3x v_max3 + 1 fmax (was 7 fmax)
                float h0 = fmaxf(fmaxf(d0[0], d1[0]), d0[1]);
                float h1 = fmaxf(fmaxf(d1[1], d0[2]), d1[2]);
                float h2 = fmaxf(fmaxf(d0[3], d1[3]), h0);
                float hm = fmaxf(h1, h2);
                if (hm >= thrmin[tt]) {
#pragma unroll
                    for (int g = 0; g < 4; g++) {
                        unsigned t = (unsigned)(t0w + tt * 16 + quad * 4 + g);
                        if (d0[g] >= thr[tt][g]) {
                            unsigned idx = atomicAdd(&cnt, 1u);
                            if (idx < CCAP) cand[idx] = (t << 17) | (unsigned)v0;
                        }
                        if (d1[g] >= thr[tt][g]) {
                            unsigned idx = atomicAdd(&cnt, 1u);
                            if (idx < CCAP) cand[idx] = (t << 17) | (unsigned)(v0 + 16);
                        }
                    }
                }
            }
        }
    }

    __syncthreads();
    unsigned n = cnt < CCAP ? cnt : CCAP;
    const float* cmb = ws + OFF_CMB;
    for (unsigned i = tid; i < n; i += 256) {
        unsigned e = cand[i];
        int t = (int)(e >> 17);
        int v = (int)(e & 0x1FFFFu);
        const float* wr = Wio + (long long)v * 20;
        float ex = bio[v];
#pragma unroll
        for (int k = 0; k < 20; k++)
            ex = fmaf(wr[k], cmb[k * SEQ + t], ex);
        unsigned key = sortable(ex);
        unsigned long long packed =
            ((unsigned long long)key << 32) | (unsigned)(VOCAB - v);
        atomicMax(&amax[t], packed);
    }
}

// ---------------------------------------------------------------------------
// K6: unpack argmax -> float index
// ---------------------------------------------------------------------------
__global__ void k_out(const unsigned long long* __restrict__ amax,
                      float* __restrict__ out) {
    int t = blockIdx.x * blockDim.x + threadIdx.x;
    if (t >= SEQ) return;
    unsigned long long p = amax[t];
    int idx = VOCAB - (int)(p & 0xFFFFFFFFu);
    out[t] = (float)idx;
}

// ---------------------------------------------------------------------------
extern "C" void kernel_launch(void* const* d_in, const int* in_sizes, int n_in,
                              void* d_out, int out_size, void* d_ws, size_t ws_size,
                              hipStream_t stream) {
    (void)in_sizes; (void)n_in; (void)out_size; (void)ws_size;
    const int*   ix  = (const int*)d_in[0];
    const float* emb = (const float*)d_in[1];
    const float* Wih = (const float*)d_in[2];
    const float* bih = (const float*)d_in[3];
    const float* Wio = (const float*)d_in[4];
    const float* bio = (const float*)d_in[5];
    float* out = (float*)d_out;
    float* ws  = (float*)d_ws;
    unsigned long long* amax = (unsigned long long*)(ws + OFF_AMAX);
    unsigned* amax1 = (unsigned*)(ws + OFF_AMAX1);

    hipLaunchKernelGGL(k_prep,   dim3(532),           dim3(256), 0, stream, ix, emb, Wih, bih, Wio, bio, ws);
    hipLaunchKernelGGL(k_scan,   dim3(1),             dim3(128), 0, stream, Wih, ws);
    hipLaunchKernelGGL(k_pack_c, dim3(33),            dim3(256), 0, stream, ws);
    hipLaunchKernelGGL(k_seed,   dim3(TBLK * SEEDSL), dim3(256), 0, stream, ws, amax1);
    hipLaunchKernelGGL(k_cand,   dim3(TBLK * VSLICE), dim3(256), 0, stream, ws, Wio, bio, amax1, amax);
    hipLaunchKernelGGL(k_out,    dim3(SEQ / 256),     dim3(256), 0, stream, amax, out);
}

// Round 2
// 346.870 us; speedup vs baseline: 1.1939x; 1.1522x over previous
//
#include <hip/hip_runtime.h>

#define SEQ   8192
#define VOCAB 128000
#define L     64
#define NCH   128   // SEQ / L

// ws layout (float offsets)
#define OFF_CMB    0        // CmbT[k][t] : [20][8192] fp32 combined, k-major
#define OFF_CVEC   163840   // cvecT[k][m][i] : [64][128][10]
#define OFF_AMAX   245760   // amax64[t] : 8192 x u64 packed
#define OFF_AMAX1  262144   // amax1[t] : 8192 x u32 sortable approx max
#define OFF_CNORM  270336   // ||c_t||_2 augmented
#define OFF_WPART  278528   // per-block W-norm partials (500)
#define OFF_WMAX   279040   // final wmax (float)
#define OFF_C32    279104   // c32[t][32] bf16 (131072 floats)
#define OFF_W32    410176   // W32[v][32] bf16 (2048000 floats)
// total 2,458,176 floats = 9.83 MB

#define TBLK   16    // t-blocks of 512 t
#define VSL2   125   // v-slices of 1024 v in k_cand (125*1024 = 128000)
#define VSPAN  1024  // v per slice
#define NIT    32    // pair-iters per slice (32 v each)
#define SEEDSL 32    // seed v-slices (32*1024 = 32768 v sampled)
#define CCAP   4096

typedef __attribute__((ext_vector_type(8))) short bf16x8;
typedef __attribute__((ext_vector_type(4))) float f32x4;

static __device__ inline unsigned short f2bf(float x) {
    unsigned u = __float_as_uint(x);
    u += 0x7FFF + ((u >> 16) & 1);          // RNE
    return (unsigned short)(u >> 16);
}
static __device__ inline unsigned sortable(float x) {
    unsigned u = __float_as_uint(x);
    return (u & 0x80000000u) ? ~u : (u | 0x80000000u);
}
static __device__ inline float unsortable(unsigned k) {
    unsigned u = (k & 0x80000000u) ? (k & 0x7FFFFFFFu) : ~k;
    return __uint_as_float(u);
}

// ---------------------------------------------------------------------------
// K1 (k_prep): blocks 0..31 = embed (+ zero amax/amax1); blocks 32..531 =
// pack [W_v,b_v] -> bf16[v][32] + per-block augmented-norm partial.
// ---------------------------------------------------------------------------
__global__ void k_prep(const int* __restrict__ ix, const float* __restrict__ emb,
                       const float* __restrict__ Wih, const float* __restrict__ bih,
                       const float* __restrict__ Wio, const float* __restrict__ bio,
                       float* __restrict__ ws) {
    int b = blockIdx.x;
    int tid = threadIdx.x;
    if (b < 32) {
        int t = b * 256 + tid;
        ((unsigned long long*)(ws + OFF_AMAX))[t] = 0ULL;
        ((unsigned*)(ws + OFF_AMAX1))[t] = 0u;

        int id = ix[t];
        float w[10];
        const float2* ep = (const float2*)(emb + (long long)id * 10);
#pragma unroll
        for (int j = 0; j < 5; j++) ((float2*)w)[j] = ep[j];
#pragma unroll
        for (int j = 0; j < 10; j++) ws[OFF_CMB + j * SEQ + t] = w[j];

        int m = t >> 6, k = t & 63;
        float* cv = ws + OFF_CVEC + (k * NCH + m) * 10;
#pragma unroll
        for (int i = 0; i < 10; i++) {
            float s = bih[i];
#pragma unroll
            for (int j = 0; j < 10; j++) s += Wih[i * 20 + j] * w[j];
            cv[i] = s;
        }
    } else {
        __shared__ float red[4];
        int bs = b - 32;
        int v = bs * 256 + tid;
        float w[20];
        const float4* r = (const float4*)(Wio + (long long)v * 20);
#pragma unroll
        for (int q = 0; q < 5; q++) ((float4*)w)[q] = r[q];
        float bv = bio[v];
        float n2 = bv * bv;
#pragma unroll
        for (int k = 0; k < 20; k++) n2 += w[k] * w[k];
        float nrm = sqrtf(n2);
        for (int off = 1; off < 64; off <<= 1)
            nrm = fmaxf(nrm, __shfl_xor(nrm, off));
        if ((tid & 63) == 0) red[tid >> 6] = nrm;
        __syncthreads();
        if (tid == 0)
            ws[OFF_WPART + bs] = fmaxf(fmaxf(red[0], red[1]), fmaxf(red[2], red[3]));

        unsigned short h[32];
#pragma unroll
        for (int k = 0; k < 20; k++) h[k] = f2bf(w[k]);
        h[20] = f2bf(bv);
#pragma unroll
        for (int k = 21; k < 32; k++) h[k] = 0;
        uint4* dst = (uint4*)((unsigned short*)(ws + OFF_W32));
#pragma unroll
        for (int i = 0; i < 4; i++) {
            uint4 u;
            u.x = (unsigned)h[8*i+0] | ((unsigned)h[8*i+1] << 16);
            u.y = (unsigned)h[8*i+2] | ((unsigned)h[8*i+3] << 16);
            u.z = (unsigned)h[8*i+4] | ((unsigned)h[8*i+5] << 16);
            u.w = (unsigned)h[8*i+6] | ((unsigned)h[8*i+7] << 16);
            dst[v * 4 + i] = u;
        }
    }
}

// ---------------------------------------------------------------------------
// K2: blocked scan of h_{t+1} = A h_t + c_t -> CmbT rows 10..19.
// ---------------------------------------------------------------------------
__global__ void k_scan(const float* __restrict__ Wih, float* __restrict__ ws) {
    __shared__ float P[100], Q[100];
    __shared__ float Dl[NCH][10];
    __shared__ float Hst[NCH][10];
    __shared__ float Hl[10];
    int tid = threadIdx.x;

    float Ar[10][10];
#pragma unroll
    for (int i = 0; i < 10; i++)
#pragma unroll
        for (int j = 0; j < 10; j++) Ar[i][j] = Wih[i * 20 + 10 + j];

    {   // phase A
        int m = tid;
        float h[10];
#pragma unroll
        for (int i = 0; i < 10; i++) h[i] = 0.f;
        const float* cvb = ws + OFF_CVEC;
        float2 buf[5];
        {
            const float2* cp = (const float2*)(cvb + m * 10);
#pragma unroll
            for (int j = 0; j < 5; j++) buf[j] = cp[j];
        }
        for (int k = 0; k < L; k++) {
            float cc[10];
#pragma unroll
            for (int j = 0; j < 5; j++) { cc[2*j] = buf[j].x; cc[2*j+1] = buf[j].y; }
            if (k + 1 < L) {
                const float2* cp = (const float2*)(cvb + ((k + 1) * NCH + m) * 10);
#pragma unroll
                for (int j = 0; j < 5; j++) buf[j] = cp[j];
            }
            float nh[10];
#pragma unroll
            for (int i = 0; i < 10; i++) {
                float s = cc[i];
#pragma unroll
                for (int j = 0; j < 10; j++) s += Ar[i][j] * h[j];
                nh[i] = s;
            }
#pragma unroll
            for (int i = 0; i < 10; i++) h[i] = nh[i];
        }
#pragma unroll
        for (int i = 0; i < 10; i++) Dl[m][i] = h[i];
    }

    if (tid < 100) P[tid] = Wih[(tid / 10) * 20 + 10 + (tid % 10)];
    __syncthreads();
    for (int it = 0; it < 6; it++) {
        if (tid < 100) {
            int i = tid / 10, j = tid % 10;
            float s = 0.f;
#pragma unroll
            for (int k = 0; k < 10; k++) s += P[i * 10 + k] * P[k * 10 + j];
            Q[tid] = s;
        }
        __syncthreads();
        if (tid < 100) P[tid] = Q[tid];
        __syncthreads();
    }

    if (tid < 10) Hl[tid] = 0.f;
    __syncthreads();
    if (tid < 10) {
        int i = tid;
        float a64[10];
#pragma unroll
        for (int j = 0; j < 10; j++) a64[j] = P[i * 10 + j];
        float hc = 0.f;
        for (int m = 0; m < NCH; m++) {
            Hst[m][i] = hc;
            float s = Dl[m][i];
#pragma unroll
            for (int j = 0; j < 10; j++) s += a64[j] * Hl[j];
            Hl[i] = s;
            hc = s;
        }
    }
    __syncthreads();

    {   // phase C
        int m = tid;
        float h[10];
#pragma unroll
        for (int i = 0; i < 10; i++) h[i] = Hst[m][i];
        const float* cvb = ws + OFF_CVEC;
        float2 buf[5];
        {
            const float2* cp = (const float2*)(cvb + m * 10);
#pragma unroll
            for (int j = 0; j < 5; j++) buf[j] = cp[j];
        }
        for (int k = 0; k < L; k++) {
            int tg = m * 64 + k;
            float cc[10];
#pragma unroll
            for (int j = 0; j < 5; j++) { cc[2*j] = buf[j].x; cc[2*j+1] = buf[j].y; }
            if (k + 1 < L) {
                const float2* cp = (const float2*)(cvb + ((k + 1) * NCH + m) * 10);
#pragma unroll
                for (int j = 0; j < 5; j++) buf[j] = cp[j];
            }
#pragma unroll
            for (int i = 0; i < 10; i++) ws[OFF_CMB + (10 + i) * SEQ + tg] = h[i];
            float nh[10];
#pragma unroll
            for (int i = 0; i < 10; i++) {
                float s = cc[i];
#pragma unroll
                for (int j = 0; j < 10; j++) s += Ar[i][j] * h[j];
                nh[i] = s;
            }
#pragma unroll
            for (int i = 0; i < 10; i++) h[i] = nh[i];
        }
    }
}

// ---------------------------------------------------------------------------
// K3: blocks 0..31 pack c -> bf16[t][32]; block 32 reduces W-norm partials.
// ---------------------------------------------------------------------------
__global__ void k_pack_c(float* __restrict__ ws) {
    int b = blockIdx.x;
    int tid = threadIdx.x;
    if (b == 32) {
        __shared__ float red[4];
        float m = 0.f;
        for (int i = tid; i < 500; i += 256) m = fmaxf(m, ws[OFF_WPART + i]);
        for (int off = 1; off < 64; off <<= 1)
            m = fmaxf(m, __shfl_xor(m, off));
        if ((tid & 63) == 0) red[tid >> 6] = m;
        __syncthreads();
        if (tid == 0)
            ws[OFF_WMAX] = fmaxf(fmaxf(red[0], red[1]), fmaxf(red[2], red[3]));
        return;
    }
    int t = b * 256 + tid;
    float c[20];
#pragma unroll
    for (int k = 0; k < 20; k++) c[k] = ws[OFF_CMB + k * SEQ + t];
    float n2 = 1.0f;
#pragma unroll
    for (int k = 0; k < 20; k++) n2 += c[k] * c[k];
    ws[OFF_CNORM + t] = sqrtf(n2);

    unsigned short h[32];
#pragma unroll
    for (int k = 0; k < 20; k++) h[k] = f2bf(c[k]);
    h[20] = f2bf(1.0f);
#pragma unroll
    for (int k = 21; k < 32; k++) h[k] = 0;
    uint4* dst = (uint4*)((unsigned short*)(ws + OFF_C32));
#pragma unroll
    for (int i = 0; i < 4; i++) {
        uint4 u;
        u.x = (unsigned)h[8*i+0] | ((unsigned)h[8*i+1] << 16);
        u.y = (unsigned)h[8*i+2] | ((unsigned)h[8*i+3] << 16);
        u.z = (unsigned)h[8*i+4] | ((unsigned)h[8*i+5] << 16);
        u.w = (unsigned)h[8*i+6] | ((unsigned)h[8*i+7] << 16);
        dst[t * 4 + i] = u;
    }
}

// ---------------------------------------------------------------------------
// K4 (k_seed): sampled approx-max, BARRIER-FREE. Grid 512 = 16 tb x 32 sl
// (32768 of 128000 v sampled -> sample max ~3.85 sigma vs true ~3.9).
// b-fragments read straight from L2 (no LDS, no __syncthreads): each b
// feeds 8 MFMAs, waves free-run, 1-deep prefetch hides L2 latency.
// ---------------------------------------------------------------------------
__global__ __launch_bounds__(256, 4)
void k_seed(const float* __restrict__ ws, unsigned* __restrict__ amax1) {
    int tid = threadIdx.x;
    int lane = tid & 63, wid = tid >> 6, quad = lane >> 4, col = lane & 15;
    int tb  = blockIdx.x >> 5;        // 0..15
    int sl  = blockIdx.x & 31;        // 0..31
    int t0w = tb * 512 + wid * 128;
    int v0s = sl * VSPAN;

    const unsigned short* c32 = (const unsigned short*)(ws + OFF_C32);
    const unsigned short* Wg  = (const unsigned short*)(ws + OFF_W32);

    bf16x8 a[8];
#pragma unroll
    for (int tt = 0; tt < 8; tt++)
        a[tt] = *(const bf16x8*)(c32 + (t0w + tt * 16 + col) * 32 + quad * 8);

    const f32x4 zero = {0.f, 0.f, 0.f, 0.f};
    float run[8][4];
#pragma unroll
    for (int tt = 0; tt < 8; tt++)
#pragma unroll
        for (int g = 0; g < 4; g++) run[tt][g] = -3.4e38f;

    const unsigned short* Wb = Wg + (unsigned)(v0s + col) * 32 + quad * 8;
    bf16x8 nb0 = *(const bf16x8*)(Wb);
    bf16x8 nb1 = *(const bf16x8*)(Wb + 512);

    for (int p = 0; p < NIT; ++p) {
        bf16x8 b0 = nb0, b1 = nb1;
        if (p + 1 < NIT) {
            const unsigned short* Wn = Wb + (p + 1) * 1024;
            nb0 = *(const bf16x8*)(Wn);
            nb1 = *(const bf16x8*)(Wn + 512);
        }
#pragma unroll
        for (int tt = 0; tt < 8; tt++) {
            f32x4 d0 = __builtin_amdgcn_mfma_f32_16x16x32_bf16(a[tt], b0, zero, 0, 0, 0);
            f32x4 d1 = __builtin_amdgcn_mfma_f32_16x16x32_bf16(a[tt], b1, zero, 0, 0, 0);
#pragma unroll
            for (int g = 0; g < 4; g++)
                run[tt][g] = fmaxf(run[tt][g], fmaxf(d0[g], d1[g]));
        }
    }

#pragma unroll
    for (int tt = 0; tt < 8; tt++)
#pragma unroll
        for (int g = 0; g < 4; g++) {
            float r = run[tt][g];
            for (int off = 1; off < 16; off <<= 1)
                r = fmaxf(r, __shfl_xor(r, off));
            if (col == 0)
                atomicMax(&amax1[t0w + tt * 16 + quad * 4 + g], sortable(r));
        }
}

// ---------------------------------------------------------------------------
// K5 (k_cand): candidate pass, BARRIER-FREE main loop. Grid 2000 =
// 125 sl x 16 tb, slice-major (consecutive blocks share the same W window
// -> ~128 KB L2-resident W per XCD). No LDS staging: b read from L2 with
// 1-deep prefetch; 4 blocks/CU. Exact fp32 epilogue with predicated u64
// atomicMax (= exact jnp.argmax semantics).
// ---------------------------------------------------------------------------
__global__ __launch_bounds__(256, 4)
void k_cand(const float* __restrict__ ws, const float* __restrict__ Wio,
            const float* __restrict__ bio, const unsigned* __restrict__ amax1,
            unsigned long long* __restrict__ amax) {
    __shared__ unsigned cand[CCAP];
    __shared__ unsigned cnt;

    int tid = threadIdx.x;
    int lane = tid & 63, wid = tid >> 6, quad = lane >> 4, col = lane & 15;
    int tb  = blockIdx.x & 15;        // t-major within a slice group
    int sl  = blockIdx.x >> 4;        // 0..124
    int t0w = tb * 512 + wid * 128;
    int v0s = sl * VSPAN;
    if (tid == 0) cnt = 0;
    __syncthreads();

    const unsigned short* c32 = (const unsigned short*)(ws + OFF_C32);
    const unsigned short* Wg  = (const unsigned short*)(ws + OFF_W32);
    float wmax = ws[OFF_WMAX];

    bf16x8 a[8];
    float thr[8][4], thrmin[8];
#pragma unroll
    for (int tt = 0; tt < 8; tt++) {
        a[tt] = *(const bf16x8*)(c32 + (t0w + tt * 16 + col) * 32 + quad * 8);
        float mn = 3.4e38f;
#pragma unroll
        for (int g = 0; g < 4; g++) {
            int t = t0w + tt * 16 + quad * 4 + g;
            float maxap = unsortable(amax1[t]);
            thr[tt][g] = maxap - (0.04f * ws[OFF_CNORM + t] * wmax + 1e-5f);
            mn = fminf(mn, thr[tt][g]);
        }
        thrmin[tt] = mn;
    }

    const f32x4 zero = {0.f, 0.f, 0.f, 0.f};
    const unsigned short* Wb = Wg + (unsigned)(v0s + col) * 32 + quad * 8;
    bf16x8 nb0 = *(const bf16x8*)(Wb);
    bf16x8 nb1 = *(const bf16x8*)(Wb + 512);

    for (int p = 0; p < NIT; ++p) {
        bf16x8 b0 = nb0, b1 = nb1;
        if (p + 1 < NIT) {
            const unsigned short* Wn = Wb + (p + 1) * 1024;
            nb0 = *(const bf16x8*)(Wn);
            nb1 = *(const bf16x8*)(Wn + 512);
        }
        int v0 = v0s + p * 32 + col;
#pragma unroll
        for (int tt = 0; tt < 8; tt++) {
            f32x4 d0 = __builtin_amdgcn_mfma_f32_16x16x32_bf16(a[tt], b0, zero, 0, 0, 0);
            f32x4 d1 = __builtin_amdgcn_mfma_f32_16x16x32_bf16(a[tt], b1, zero, 0, 0, 0);
            float h0 = fmaxf(fmaxf(d0[0], d1[0]), fmaxf(d0[1], d1[1]));
            float h1 = fmaxf(fmaxf(d0[2], d1[2]), fmaxf(d0[3], d1[3]));
            float hm = fmaxf(h0, h1);
            if (hm >= thrmin[tt]) {
#pragma unroll
                for (int g = 0; g < 4; g++) {
                    unsigned t = (unsigned)(t0w + tt * 16 + quad * 4 + g);
                    if (d0[g] >= thr[tt][g]) {
                        unsigned idx = atomicAdd(&cnt, 1u);
                        if (idx < CCAP) cand[idx] = (t << 17) | (unsigned)v0;
                    }
                    if (d1[g] >= thr[tt][g]) {
                        unsigned idx = atomicAdd(&cnt, 1u);
                        if (idx < CCAP) cand[idx] = (t << 17) | (unsigned)(v0 + 16);
                    }
                }
            }
        }
    }

    __syncthreads();
    unsigned n = cnt < CCAP ? cnt : CCAP;
    const float* cmb = ws + OFF_CMB;
    for (unsigned i = tid; i < n; i += 256) {
        unsigned e = cand[i];
        int t = (int)(e >> 17);
        int v = (int)(e & 0x1FFFFu);
        const float* wr = Wio + (long long)v * 20;
        float ex = bio[v];
#pragma unroll
        for (int k = 0; k < 20; k++)
            ex = fmaf(wr[k], cmb[k * SEQ + t], ex);
        unsigned key = sortable(ex);
        unsigned long long packed =
            ((unsigned long long)key << 32) | (unsigned)(VOCAB - v);
        unsigned long long cur = amax[t];      // cheap pre-filter (stale-safe:
        if (packed > cur)                      // stale reads only under-filter)
            atomicMax(&amax[t], packed);
    }
}

// ---------------------------------------------------------------------------
// K6: unpack argmax -> float index
// ---------------------------------------------------------------------------
__global__ void k_out(const unsigned long long* __restrict__ amax,
                      float* __restrict__ out) {
    int t = blockIdx.x * blockDim.x + threadIdx.x;
    if (t >= SEQ) return;
    unsigned long long p = amax[t];
    int idx = VOCAB - (int)(p & 0xFFFFFFFFu);
    out[t] = (float)idx;
}

// ---------------------------------------------------------------------------
extern "C" void kernel_launch(void* const* d_in, const int* in_sizes, int n_in,
                              void* d_out, int out_size, void* d_ws, size_t ws_size,
                              hipStream_t stream) {
    (void)in_sizes; (void)n_in; (void)out_size; (void)ws_size;
    const int*   ix  = (const int*)d_in[0];
    const float* emb = (const float*)d_in[1];
    const float* Wih = (const float*)d_in[2];
    const float* bih = (const float*)d_in[3];
    const float* Wio = (const float*)d_in[4];
    const float* bio = (const float*)d_in[5];
    float* out = (float*)d_out;
    float* ws  = (float*)d_ws;
    unsigned long long* amax = (unsigned long long*)(ws + OFF_AMAX);
    unsigned* amax1 = (unsigned*)(ws + OFF_AMAX1);

    hipLaunchKernelGGL(k_prep,   dim3(532),           dim3(256), 0, stream, ix, emb, Wih, bih, Wio, bio, ws);
    hipLaunchKernelGGL(k_scan,   dim3(1),             dim3(128), 0, stream, Wih, ws);
    hipLaunchKernelGGL(k_pack_c, dim3(33),            dim3(256), 0, stream, ws);
    hipLaunchKernelGGL(k_seed,   dim3(TBLK * SEEDSL), dim3(256), 0, stream, ws, amax1);
    hipLaunchKernelGGL(k_cand,   dim3(TBLK * VSL2),   dim3(256), 0, stream, ws, Wio, bio, amax1, amax);
    hipLaunchKernelGGL(k_out,    dim3(SEQ / 256),     dim3(256), 0, stream, amax, out);
}

// Round 3
// 300.551 us; speedup vs baseline: 1.3779x; 1.1541x over previous
//
#include <hip/hip_runtime.h>

#define SEQ   8192
#define VOCAB 128000
#define L     64
#define NCH   128   // SEQ / L

// ws layout (float offsets)
#define OFF_CMB    0        // CmbT[k][t] : [20][8192] fp32 combined, k-major
#define OFF_CVEC   163840   // cvecT[k][m][i] : [64][128][10]
#define OFF_AMAX   245760   // amax64[t] : 8192 x u64 packed
#define OFF_AMAX1  262144   // amax1[t] : 8192 x u32 sortable approx max
#define OFF_CNORM  270336   // ||c_t||_2 augmented
#define OFF_WPART  278528   // per-block W-norm partials (500)
#define OFF_WMAX   279040   // final wmax (float)
#define OFF_C32    279104   // c32[t][32] bf16 (131072 floats)
#define OFF_W32    410176   // W32[v][32] bf16 (2048000 floats)
// total 2,458,176 floats = 9.83 MB

#define TBLK   16    // t-blocks of 512 t in k_cand
#define VSL2   125   // v-slices of 1024 v in k_cand (125*1024 = 128000)
#define VSPAN  1024  // v per slice
#define NIT    32    // pair-iters per slice (32 v each)
#define SEEDTB 32    // seed t-blocks of 256 t
#define SEEDSL 32    // seed v-slices (32*1024 = 32768 v sampled)
#define CCAP   4096

typedef __attribute__((ext_vector_type(8))) short bf16x8;
typedef __attribute__((ext_vector_type(4))) float f32x4;

static __device__ inline unsigned short f2bf(float x) {
    unsigned u = __float_as_uint(x);
    u += 0x7FFF + ((u >> 16) & 1);          // RNE
    return (unsigned short)(u >> 16);
}
static __device__ inline unsigned sortable(float x) {
    unsigned u = __float_as_uint(x);
    return (u & 0x80000000u) ? ~u : (u | 0x80000000u);
}
static __device__ inline float unsortable(unsigned k) {
    unsigned u = (k & 0x80000000u) ? (k & 0x7FFFFFFFu) : ~k;
    return __uint_as_float(u);
}

// ---------------------------------------------------------------------------
// K1 (k_prep): blocks 0..31 = embed (+ zero amax/amax1); blocks 32..531 =
// pack [W_v,b_v] -> bf16[v][32] + per-block augmented-norm partial.
// ---------------------------------------------------------------------------
__global__ void k_prep(const int* __restrict__ ix, const float* __restrict__ emb,
                       const float* __restrict__ Wih, const float* __restrict__ bih,
                       const float* __restrict__ Wio, const float* __restrict__ bio,
                       float* __restrict__ ws) {
    int b = blockIdx.x;
    int tid = threadIdx.x;
    if (b < 32) {
        int t = b * 256 + tid;
        ((unsigned long long*)(ws + OFF_AMAX))[t] = 0ULL;
        ((unsigned*)(ws + OFF_AMAX1))[t] = 0u;

        int id = ix[t];
        float w[10];
        const float2* ep = (const float2*)(emb + (long long)id * 10);
#pragma unroll
        for (int j = 0; j < 5; j++) ((float2*)w)[j] = ep[j];
#pragma unroll
        for (int j = 0; j < 10; j++) ws[OFF_CMB + j * SEQ + t] = w[j];

        int m = t >> 6, k = t & 63;
        float* cv = ws + OFF_CVEC + (k * NCH + m) * 10;
#pragma unroll
        for (int i = 0; i < 10; i++) {
            float s = bih[i];
#pragma unroll
            for (int j = 0; j < 10; j++) s += Wih[i * 20 + j] * w[j];
            cv[i] = s;
        }
    } else {
        __shared__ float red[4];
        int bs = b - 32;
        int v = bs * 256 + tid;
        float w[20];
        const float4* r = (const float4*)(Wio + (long long)v * 20);
#pragma unroll
        for (int q = 0; q < 5; q++) ((float4*)w)[q] = r[q];
        float bv = bio[v];
        float n2 = bv * bv;
#pragma unroll
        for (int k = 0; k < 20; k++) n2 += w[k] * w[k];
        float nrm = sqrtf(n2);
        for (int off = 1; off < 64; off <<= 1)
            nrm = fmaxf(nrm, __shfl_xor(nrm, off));
        if ((tid & 63) == 0) red[tid >> 6] = nrm;
        __syncthreads();
        if (tid == 0)
            ws[OFF_WPART + bs] = fmaxf(fmaxf(red[0], red[1]), fmaxf(red[2], red[3]));

        unsigned short h[32];
#pragma unroll
        for (int k = 0; k < 20; k++) h[k] = f2bf(w[k]);
        h[20] = f2bf(bv);
#pragma unroll
        for (int k = 21; k < 32; k++) h[k] = 0;
        uint4* dst = (uint4*)((unsigned short*)(ws + OFF_W32));
#pragma unroll
        for (int i = 0; i < 4; i++) {
            uint4 u;
            u.x = (unsigned)h[8*i+0] | ((unsigned)h[8*i+1] << 16);
            u.y = (unsigned)h[8*i+2] | ((unsigned)h[8*i+3] << 16);
            u.z = (unsigned)h[8*i+4] | ((unsigned)h[8*i+5] << 16);
            u.w = (unsigned)h[8*i+6] | ((unsigned)h[8*i+7] << 16);
            dst[v * 4 + i] = u;
        }
    }
}

// ---------------------------------------------------------------------------
// K2: blocked scan of h_{t+1} = A h_t + c_t -> CmbT rows 10..19.
// ---------------------------------------------------------------------------
__global__ void k_scan(const float* __restrict__ Wih, float* __restrict__ ws) {
    __shared__ float P[100], Q[100];
    __shared__ float Dl[NCH][10];
    __shared__ float Hst[NCH][10];
    __shared__ float Hl[10];
    int tid = threadIdx.x;

    float Ar[10][10];
#pragma unroll
    for (int i = 0; i < 10; i++)
#pragma unroll
        for (int j = 0; j < 10; j++) Ar[i][j] = Wih[i * 20 + 10 + j];

    {   // phase A
        int m = tid;
        float h[10];
#pragma unroll
        for (int i = 0; i < 10; i++) h[i] = 0.f;
        const float* cvb = ws + OFF_CVEC;
        float2 buf[5];
        {
            const float2* cp = (const float2*)(cvb + m * 10);
#pragma unroll
            for (int j = 0; j < 5; j++) buf[j] = cp[j];
        }
        for (int k = 0; k < L; k++) {
            float cc[10];
#pragma unroll
            for (int j = 0; j < 5; j++) { cc[2*j] = buf[j].x; cc[2*j+1] = buf[j].y; }
            if (k + 1 < L) {
                const float2* cp = (const float2*)(cvb + ((k + 1) * NCH + m) * 10);
#pragma unroll
                for (int j = 0; j < 5; j++) buf[j] = cp[j];
            }
            float nh[10];
#pragma unroll
            for (int i = 0; i < 10; i++) {
                float s = cc[i];
#pragma unroll
                for (int j = 0; j < 10; j++) s += Ar[i][j] * h[j];
                nh[i] = s;
            }
#pragma unroll
            for (int i = 0; i < 10; i++) h[i] = nh[i];
        }
#pragma unroll
        for (int i = 0; i < 10; i++) Dl[m][i] = h[i];
    }

    if (tid < 100) P[tid] = Wih[(tid / 10) * 20 + 10 + (tid % 10)];
    __syncthreads();
    for (int it = 0; it < 6; it++) {
        if (tid < 100) {
            int i = tid / 10, j = tid % 10;
            float s = 0.f;
#pragma unroll
            for (int k = 0; k < 10; k++) s += P[i * 10 + k] * P[k * 10 + j];
            Q[tid] = s;
        }
        __syncthreads();
        if (tid < 100) P[tid] = Q[tid];
        __syncthreads();
    }

    if (tid < 10) Hl[tid] = 0.f;
    __syncthreads();
    if (tid < 10) {
        int i = tid;
        float a64[10];
#pragma unroll
        for (int j = 0; j < 10; j++) a64[j] = P[i * 10 + j];
        float hc = 0.f;
        for (int m = 0; m < NCH; m++) {
            Hst[m][i] = hc;
            float s = Dl[m][i];
#pragma unroll
            for (int j = 0; j < 10; j++) s += a64[j] * Hl[j];
            Hl[i] = s;
            hc = s;
        }
    }
    __syncthreads();

    {   // phase C
        int m = tid;
        float h[10];
#pragma unroll
        for (int i = 0; i < 10; i++) h[i] = Hst[m][i];
        const float* cvb = ws + OFF_CVEC;
        float2 buf[5];
        {
            const float2* cp = (const float2*)(cvb + m * 10);
#pragma unroll
            for (int j = 0; j < 5; j++) buf[j] = cp[j];
        }
        for (int k = 0; k < L; k++) {
            int tg = m * 64 + k;
            float cc[10];
#pragma unroll
            for (int j = 0; j < 5; j++) { cc[2*j] = buf[j].x; cc[2*j+1] = buf[j].y; }
            if (k + 1 < L) {
                const float2* cp = (const float2*)(cvb + ((k + 1) * NCH + m) * 10);
#pragma unroll
                for (int j = 0; j < 5; j++) buf[j] = cp[j];
            }
#pragma unroll
            for (int i = 0; i < 10; i++) ws[OFF_CMB + (10 + i) * SEQ + tg] = h[i];
            float nh[10];
#pragma unroll
            for (int i = 0; i < 10; i++) {
                float s = cc[i];
#pragma unroll
                for (int j = 0; j < 10; j++) s += Ar[i][j] * h[j];
                nh[i] = s;
            }
#pragma unroll
            for (int i = 0; i < 10; i++) h[i] = nh[i];
        }
    }
}

// ---------------------------------------------------------------------------
// K3: blocks 0..31 pack c -> bf16[t][32]; block 32 reduces W-norm partials.
// ---------------------------------------------------------------------------
__global__ void k_pack_c(float* __restrict__ ws) {
    int b = blockIdx.x;
    int tid = threadIdx.x;
    if (b == 32) {
        __shared__ float red[4];
        float m = 0.f;
        for (int i = tid; i < 500; i += 256) m = fmaxf(m, ws[OFF_WPART + i]);
        for (int off = 1; off < 64; off <<= 1)
            m = fmaxf(m, __shfl_xor(m, off));
        if ((tid & 63) == 0) red[tid >> 6] = m;
        __syncthreads();
        if (tid == 0)
            ws[OFF_WMAX] = fmaxf(fmaxf(red[0], red[1]), fmaxf(red[2], red[3]));
        return;
    }
    int t = b * 256 + tid;
    float c[20];
#pragma unroll
    for (int k = 0; k < 20; k++) c[k] = ws[OFF_CMB + k * SEQ + t];
    float n2 = 1.0f;
#pragma unroll
    for (int k = 0; k < 20; k++) n2 += c[k] * c[k];
    ws[OFF_CNORM + t] = sqrtf(n2);

    unsigned short h[32];
#pragma unroll
    for (int k = 0; k < 20; k++) h[k] = f2bf(c[k]);
    h[20] = f2bf(1.0f);
#pragma unroll
    for (int k = 21; k < 32; k++) h[k] = 0;
    uint4* dst = (uint4*)((unsigned short*)(ws + OFF_C32));
#pragma unroll
    for (int i = 0; i < 4; i++) {
        uint4 u;
        u.x = (unsigned)h[8*i+0] | ((unsigned)h[8*i+1] << 16);
        u.y = (unsigned)h[8*i+2] | ((unsigned)h[8*i+3] << 16);
        u.z = (unsigned)h[8*i+4] | ((unsigned)h[8*i+5] << 16);
        u.w = (unsigned)h[8*i+6] | ((unsigned)h[8*i+7] << 16);
        dst[t * 4 + i] = u;
    }
}

// ---------------------------------------------------------------------------
// K4 (k_seed): sampled approx-max, branch/barrier-free. Grid 1024 =
// 32 t-blocks (256 t) x 32 v-slices (32768 v sampled) -> full-device
// occupancy in ONE round (was 512 blocks = 2/CU with latency exposed).
// Per wave: 64 t (4 a-frags), b streamed from L2 with 1-deep prefetch.
// ---------------------------------------------------------------------------
__global__ __launch_bounds__(256, 4)
void k_seed(const float* __restrict__ ws, unsigned* __restrict__ amax1) {
    int tid = threadIdx.x;
    int lane = tid & 63, wid = tid >> 6, quad = lane >> 4, col = lane & 15;
    int tb  = blockIdx.x >> 5;        // 0..31 (256 t each)
    int sl  = blockIdx.x & 31;        // 0..31
    int t0w = tb * 256 + wid * 64;
    int v0s = sl * VSPAN;

    const unsigned short* c32 = (const unsigned short*)(ws + OFF_C32);
    const unsigned short* Wg  = (const unsigned short*)(ws + OFF_W32);

    bf16x8 a[4];
#pragma unroll
    for (int tt = 0; tt < 4; tt++)
        a[tt] = *(const bf16x8*)(c32 + (t0w + tt * 16 + col) * 32 + quad * 8);

    const f32x4 zero = {0.f, 0.f, 0.f, 0.f};
    float run[4][4];
#pragma unroll
    for (int tt = 0; tt < 4; tt++)
#pragma unroll
        for (int g = 0; g < 4; g++) run[tt][g] = -3.4e38f;

    const unsigned short* Wb = Wg + (unsigned)(v0s + col) * 32 + quad * 8;
    bf16x8 nb0 = *(const bf16x8*)(Wb);
    bf16x8 nb1 = *(const bf16x8*)(Wb + 512);

    for (int p = 0; p < NIT; ++p) {
        bf16x8 b0 = nb0, b1 = nb1;
        int pn = (p + 1 < NIT) ? p + 1 : p;
        const unsigned short* Wn = Wb + pn * 1024;
        nb0 = *(const bf16x8*)(Wn);
        nb1 = *(const bf16x8*)(Wn + 512);
#pragma unroll
        for (int tt = 0; tt < 4; tt++) {
            f32x4 d0 = __builtin_amdgcn_mfma_f32_16x16x32_bf16(a[tt], b0, zero, 0, 0, 0);
            f32x4 d1 = __builtin_amdgcn_mfma_f32_16x16x32_bf16(a[tt], b1, zero, 0, 0, 0);
#pragma unroll
            for (int g = 0; g < 4; g++)
                run[tt][g] = fmaxf(run[tt][g], fmaxf(d0[g], d1[g]));
        }
    }

#pragma unroll
    for (int tt = 0; tt < 4; tt++)
#pragma unroll
        for (int g = 0; g < 4; g++) {
            float r = run[tt][g];
            for (int off = 1; off < 16; off <<= 1)
                r = fmaxf(r, __shfl_xor(r, off));
            if (col == 0)
                atomicMax(&amax1[t0w + tt * 16 + quad * 4 + g], sortable(r));
        }
}

// ---------------------------------------------------------------------------
// K5 (k_cand): BRANCH-FREE hot loop. Per iter: 16 MFMA + per-row compares
// folded into a per-lane 32-bit hit mask (bit p). No exec-mask churn in the
// loop => compiler can pipeline MFMAs. A wave-uniform recheck pass then
// walks the OR-reduced mask (expected ~126 true hits per block), redoes the
// 2 MFMAs for each flagged p (deterministic => identical d), and pushes
// candidates in cold code. Exact fp32 epilogue unchanged (= jnp.argmax).
// ---------------------------------------------------------------------------
__global__ __launch_bounds__(256, 4)
void k_cand(const float* __restrict__ ws, const float* __restrict__ Wio,
            const float* __restrict__ bio, const unsigned* __restrict__ amax1,
            unsigned long long* __restrict__ amax) {
    __shared__ unsigned cand[CCAP];
    __shared__ unsigned cnt;

    int tid = threadIdx.x;
    int lane = tid & 63, wid = tid >> 6, quad = lane >> 4, col = lane & 15;
    int tb  = blockIdx.x & 15;        // consecutive blocks share W window
    int sl  = blockIdx.x >> 4;        // 0..124
    int t0w = tb * 512 + wid * 128;
    int v0s = sl * VSPAN;
    if (tid == 0) cnt = 0;
    __syncthreads();

    const unsigned short* c32 = (const unsigned short*)(ws + OFF_C32);
    const unsigned short* Wg  = (const unsigned short*)(ws + OFF_W32);
    float wmax = ws[OFF_WMAX];

    bf16x8 a[8];
    float thr[8][4];
#pragma unroll
    for (int tt = 0; tt < 8; tt++) {
        a[tt] = *(const bf16x8*)(c32 + (t0w + tt * 16 + col) * 32 + quad * 8);
#pragma unroll
        for (int g = 0; g < 4; g++) {
            int t = t0w + tt * 16 + quad * 4 + g;
            float maxap = unsortable(amax1[t]);
            thr[tt][g] = maxap - (0.04f * ws[OFF_CNORM + t] * wmax + 1e-5f);
        }
    }

    const f32x4 zero = {0.f, 0.f, 0.f, 0.f};
    const unsigned short* Wb = Wg + (unsigned)(v0s + col) * 32 + quad * 8;
    bf16x8 nb0 = *(const bf16x8*)(Wb);
    bf16x8 nb1 = *(const bf16x8*)(Wb + 512);

    unsigned mask[8];
#pragma unroll
    for (int tt = 0; tt < 8; tt++) mask[tt] = 0u;

    for (int p = 0; p < NIT; ++p) {
        bf16x8 b0 = nb0, b1 = nb1;
        int pn = (p + 1 < NIT) ? p + 1 : p;
        const unsigned short* Wn = Wb + pn * 1024;
        nb0 = *(const bf16x8*)(Wn);
        nb1 = *(const bf16x8*)(Wn + 512);
        unsigned bit = 1u << p;
#pragma unroll
        for (int tt = 0; tt < 8; tt++) {
            f32x4 d0 = __builtin_amdgcn_mfma_f32_16x16x32_bf16(a[tt], b0, zero, 0, 0, 0);
            f32x4 d1 = __builtin_amdgcn_mfma_f32_16x16x32_bf16(a[tt], b1, zero, 0, 0, 0);
            unsigned hit = 0u;
#pragma unroll
            for (int g = 0; g < 4; g++) {
                float mg = fmaxf(d0[g], d1[g]);
                hit |= (mg >= thr[tt][g]) ? bit : 0u;
            }
            mask[tt] |= hit;
        }
    }

    // --- recheck: wave-uniform walk of flagged iters (cold path) ---
#pragma unroll
    for (int tt = 0; tt < 8; tt++) {
        unsigned m = mask[tt];
        for (int off = 1; off < 64; off <<= 1)
            m |= __shfl_xor(m, off);          // wave-OR -> uniform
        while (m) {
            int p = __ffs(m) - 1;
            m &= m - 1;
            const unsigned short* Wp = Wb + p * 1024;
            bf16x8 b0 = *(const bf16x8*)(Wp);
            bf16x8 b1 = *(const bf16x8*)(Wp + 512);
            f32x4 d0 = __builtin_amdgcn_mfma_f32_16x16x32_bf16(a[tt], b0, zero, 0, 0, 0);
            f32x4 d1 = __builtin_amdgcn_mfma_f32_16x16x32_bf16(a[tt], b1, zero, 0, 0, 0);
            int v0 = v0s + p * 32 + col;
#pragma unroll
            for (int g = 0; g < 4; g++) {
                unsigned t = (unsigned)(t0w + tt * 16 + quad * 4 + g);
                if (d0[g] >= thr[tt][g]) {
                    unsigned idx = atomicAdd(&cnt, 1u);
                    if (idx < CCAP) cand[idx] = (t << 17) | (unsigned)v0;
                }
                if (d1[g] >= thr[tt][g]) {
                    unsigned idx = atomicAdd(&cnt, 1u);
                    if (idx < CCAP) cand[idx] = (t << 17) | (unsigned)(v0 + 16);
                }
            }
        }
    }

    __syncthreads();
    unsigned n = cnt < CCAP ? cnt : CCAP;
    const float* cmb = ws + OFF_CMB;
    for (unsigned i = tid; i < n; i += 256) {
        unsigned e = cand[i];
        int t = (int)(e >> 17);
        int v = (int)(e & 0x1FFFFu);
        const float* wr = Wio + (long long)v * 20;
        float ex = bio[v];
#pragma unroll
        for (int k = 0; k < 20; k++)
            ex = fmaf(wr[k], cmb[k * SEQ + t], ex);
        unsigned key = sortable(ex);
        unsigned long long packed =
            ((unsigned long long)key << 32) | (unsigned)(VOCAB - v);
        unsigned long long cur = amax[t];      // stale-safe pre-filter
        if (packed > cur)
            atomicMax(&amax[t], packed);
    }
}

// ---------------------------------------------------------------------------
// K6: unpack argmax -> float index
// ---------------------------------------------------------------------------
__global__ void k_out(const unsigned long long* __restrict__ amax,
                      float* __restrict__ out) {
    int t = blockIdx.x * blockDim.x + threadIdx.x;
    if (t >= SEQ) return;
    unsigned long long p = amax[t];
    int idx = VOCAB - (int)(p & 0xFFFFFFFFu);
    out[t] = (float)idx;
}

// ---------------------------------------------------------------------------
extern "C" void kernel_launch(void* const* d_in, const int* in_sizes, int n_in,
                              void* d_out, int out_size, void* d_ws, size_t ws_size,
                              hipStream_t stream) {
    (void)in_sizes; (void)n_in; (void)out_size; (void)ws_size;
    const int*   ix  = (const int*)d_in[0];
    const float* emb = (const float*)d_in[1];
    const float* Wih = (const float*)d_in[2];
    const float* bih = (const float*)d_in[3];
    const float* Wio = (const float*)d_in[4];
    const float* bio = (const float*)d_in[5];
    float* out = (float*)d_out;
    float* ws  = (float*)d_ws;
    unsigned long long* amax = (unsigned long long*)(ws + OFF_AMAX);
    unsigned* amax1 = (unsigned*)(ws + OFF_AMAX1);

    hipLaunchKernelGGL(k_prep,   dim3(532),             dim3(256), 0, stream, ix, emb, Wih, bih, Wio, bio, ws);
    hipLaunchKernelGGL(k_scan,   dim3(1),               dim3(128), 0, stream, Wih, ws);
    hipLaunchKernelGGL(k_pack_c, dim3(33),              dim3(256), 0, stream, ws);
    hipLaunchKernelGGL(k_seed,   dim3(SEEDTB * SEEDSL), dim3(256), 0, stream, ws, amax1);
    hipLaunchKernelGGL(k_cand,   dim3(TBLK * VSL2),     dim3(256), 0, stream, ws, Wio, bio, amax1, amax);
    hipLaunchKernelGGL(k_out,    dim3(SEQ / 256),       dim3(256), 0, stream, amax, out);
}